// Round 4
// baseline (335.550 us; speedup 1.0000x reference)
//
#include <hip/hip_runtime.h>

#define MAXG 4
#define CPB 8                         // channels per chunk
#define NCHUNK 2                      // chunks (of CPB channels) per block, pipelined
#define ROWS_MAX 30                   // max region rows (roi<=28 -> span<=30)
#define LDS_STRIDE 37                 // odd row stride spreads banks: bank=(5r+x)%32
#define CH_STRIDE (ROWS_MAX * LDS_STRIDE)   // 1110 floats per channel

// Block = (roi, pair of 8-channel chunks), 512 threads.
// Geometry tables are per-ROI -> built once, shared by both chunks.
// Pipeline: stage A -> barrier -> [prefetch B to regs || compute A] -> barrier
//           -> regs->LDS -> barrier -> compute B.
__global__ __launch_bounds__(512, 8) void roi_align_kernel(
    const float* __restrict__ feat,
    const float* __restrict__ rois,
    float* __restrict__ out,
    int C, int H, int W)
{
    const int n    = blockIdx.x;
    const int cblk = blockIdx.y;
    const int t    = threadIdx.x;

    __shared__ float s_feat[CPB * CH_STRIDE];   // 35.5 KB
    __shared__ int4  s_ypack[28];               // {rlo*37, rhi*37, bits(wy0), bits(wy1)}
    __shared__ int4  s_xpack[28];               // {xlo-x0a, xhi-x0a, bits(wx0), bits(wx1)}

    const float* roi = rois + (size_t)n * 5;
    const int   b  = (int)roi[0];
    const float x1 = roi[1], y1 = roi[2], x2 = roi[3], y2 = roi[4];
    const float roi_w = fmaxf(x2 - x1, 1.0f);
    const float roi_h = fmaxf(y2 - y1, 1.0f);
    const float bin_h = roi_h / 7.0f;
    const float bin_w = roi_w / 7.0f;
    int gh = (int)ceilf(roi_h / 7.0f); gh = min(max(gh, 1), MAXG);
    int gw = (int)ceilf(roi_w / 7.0f); gw = min(max(gw, 1), MAXG);
    const float inv_count = 1.0f / (float)(gh * gw);

    auto lo_of = [](float pos, int size) {
        float p = fmaxf(pos, 0.0f);
        return min((int)floorf(p), size - 1);
    };
    const int y0 = lo_of(y1 + 0.5f * bin_h / (float)gh, H);
    const int yE = min(lo_of(y1 + 6.0f * bin_h + ((float)(gh - 1) + 0.5f) * bin_h / (float)gh, H) + 1, H - 1);
    const int x0 = lo_of(x1 + 0.5f * bin_w / (float)gw, W);
    const int xE = min(lo_of(x1 + 6.0f * bin_w + ((float)(gw - 1) + 0.5f) * bin_w / (float)gw, W) + 1, W - 1);
    const int rh    = min(yE - y0 + 1, ROWS_MAX);
    const int x0a   = x0 & ~3;                   // 16B-align region start
    const int spanA = min(xE - x0a + 1, 33);     // cols needed from x0a
    const int CM    = W - 4 - x0a;               // max aligned quad start in-row

    // --- geometry tables, once per block (shared by both chunks)
    if (t < 28) {
        const int py = t >> 2, g = t & 3;
        float pos  = y1 + (float)py * bin_h + ((float)g + 0.5f) * bin_h / (float)gh;
        bool valid = (pos >= -1.0f) && (pos <= (float)H);
        float p = fmaxf(pos, 0.0f);
        int lo  = min((int)floorf(p), H - 1);
        int hi  = min(lo + 1, H - 1);
        if (lo >= H - 1) p = (float)(H - 1);
        float frac = p - (float)lo;
        float m = valid ? 1.0f : 0.0f;
        s_ypack[t] = make_int4((lo - y0) * LDS_STRIDE, (hi - y0) * LDS_STRIDE,
                               __float_as_int((1.0f - frac) * m),
                               __float_as_int(frac * m));
    } else if (t < 56) {
        const int u = t - 28;
        const int px = u >> 2, g = u & 3;
        float pos  = x1 + (float)px * bin_w + ((float)g + 0.5f) * bin_w / (float)gw;
        bool valid = (pos >= -1.0f) && (pos <= (float)W);
        float p = fmaxf(pos, 0.0f);
        int lo  = min((int)floorf(p), W - 1);
        int hi  = min(lo + 1, W - 1);
        if (lo >= W - 1) p = (float)(W - 1);
        float frac = p - (float)lo;
        float m = valid ? 1.0f : 0.0f;
        s_xpack[u] = make_int4(lo - x0a, hi - x0a,
                               __float_as_int((1.0f - frac) * m),
                               __float_as_int(frac * m));
    }

    // --- k-invariant staging coordinates (ch steps by +2 per k)
    const int  ch0    = t >> 8;                  // 0 or 1
    const int  r      = (t >> 3) & 31;
    const int  q      = t & 7;
    const int  q4     = q << 2;
    const bool rowok  = r < rh;
    const bool qok    = rowok && (q4 < spanA);
    const bool tailok = rowok && (q == 7) && (spanA == 33);
    const int  col    = min(q4, CM);
    const int  colT   = min(32, CM);

    const size_t HW = (size_t)H * W;
    const int c0A = cblk * (CPB * NCHUNK);       // chunk A channels [c0A, c0A+8)
    const int c0B = c0A + CPB;                   // chunk B channels
    const float* fbase = feat + ((size_t)b * C) * HW + (size_t)y0 * W + x0a;

    // --- stage chunk A directly into LDS
    {
        const float* gp = fbase + (size_t)(c0A + ch0) * HW + (size_t)r * W;
        float* sp = s_feat + ch0 * CH_STRIDE + r * LDS_STRIDE;
        #pragma unroll
        for (int k = 0; k < 4; ++k) {
            if (qok) {
                const float4 v = *(const float4*)(gp + col);
                sp[col + 0] = v.x; sp[col + 1] = v.y; sp[col + 2] = v.z; sp[col + 3] = v.w;
            }
            if (tailok) {
                const float4 v = *(const float4*)(gp + colT);
                sp[colT + 0] = v.x; sp[colT + 1] = v.y; sp[colT + 2] = v.z; sp[colT + 3] = v.w;
            }
            gp += 2 * HW; sp += 2 * CH_STRIDE;
        }
    }
    __syncthreads();

    // --- prefetch chunk B into registers (overlaps with compute A below)
    float4 pv[4], pvT[4];
    {
        const float* gp = fbase + (size_t)(c0B + ch0) * HW + (size_t)r * W;
        #pragma unroll
        for (int k = 0; k < 4; ++k) {
            if (qok)    pv[k]  = *(const float4*)(gp + col);
            if (tailok) pvT[k] = *(const float4*)(gp + colT);
            gp += 2 * HW;
        }
    }

    // --- compute one chunk: thread t -> (channel t/49, pixel t%49)
    auto compute_chunk = [&](int c0) {
        if (t < CPB * 49) {
            const int cl  = t / 49;
            const int pix = t - cl * 49;
            const int py  = pix / 7;
            const int px  = pix - py * 7;
            const float* sp = s_feat + cl * CH_STRIDE;

            int4 xp[4];
            #pragma unroll
            for (int g = 0; g < 4; ++g) xp[g] = s_xpack[(px << 2) + g];

            float acc = 0.0f;
            #pragma unroll
            for (int gy = 0; gy < MAXG; ++gy) {
                if (gy < gh) {
                    const int4 yp = s_ypack[(py << 2) + gy];
                    const float wy0 = __int_as_float(yp.z);
                    const float wy1 = __int_as_float(yp.w);
                    #pragma unroll
                    for (int gx = 0; gx < MAXG; ++gx) {
                        if (gx < gw) {
                            const float wx0 = __int_as_float(xp[gx].z);
                            const float wx1 = __int_as_float(xp[gx].w);
                            const float v00 = sp[yp.x + xp[gx].x];
                            const float v01 = sp[yp.x + xp[gx].y];
                            const float v10 = sp[yp.y + xp[gx].x];
                            const float v11 = sp[yp.y + xp[gx].y];
                            acc += wy0 * (wx0 * v00 + wx1 * v01)
                                 + wy1 * (wx0 * v10 + wx1 * v11);
                        }
                    }
                }
            }
            out[((size_t)n * C + c0) * 49 + t] = acc * inv_count;
        }
    };

    compute_chunk(c0A);
    __syncthreads();                 // everyone done reading LDS chunk A

    // --- write prefetched chunk B into LDS
    {
        float* sp = s_feat + ch0 * CH_STRIDE + r * LDS_STRIDE;
        #pragma unroll
        for (int k = 0; k < 4; ++k) {
            if (qok) {
                sp[col + 0] = pv[k].x; sp[col + 1] = pv[k].y;
                sp[col + 2] = pv[k].z; sp[col + 3] = pv[k].w;
            }
            if (tailok) {
                sp[colT + 0] = pvT[k].x; sp[colT + 1] = pvT[k].y;
                sp[colT + 2] = pvT[k].z; sp[colT + 3] = pvT[k].w;
            }
            sp += 2 * CH_STRIDE;
        }
    }
    __syncthreads();

    compute_chunk(c0B);
}

extern "C" void kernel_launch(void* const* d_in, const int* in_sizes, int n_in,
                              void* d_out, int out_size, void* d_ws, size_t ws_size,
                              hipStream_t stream) {
    const float* feat = (const float*)d_in[0];
    const float* rois = (const float*)d_in[1];
    float* out = (float*)d_out;

    const int C = 256, H = 200, W = 272;
    const int N = in_sizes[1] / 5;   // 512

    dim3 grid(N, C / (CPB * NCHUNK));            // 512 x 16
    roi_align_kernel<<<grid, 512, 0, stream>>>(feat, rois, out, C, H, W);
}

// Round 5
// 324.016 us; speedup vs baseline: 1.0356x; 1.0356x over previous
//
#include <hip/hip_runtime.h>

#define MAXG 4
#define CPB 8                        // channels per block = 4 pairs
#define UCOLS 33                     // region cols 0..32 per row
#define PSTRIDE 5                    // float2 stride per (row,col): 4 pairs + 1 pad (odd)
#define YMUL (UCOLS * PSTRIDE)       // 165: row -> float2-index
#define S2LEN ((29 * UCOLS + 32) * PSTRIDE + 8)   // 4957 float2 ~= 39.7 KB

// Block = (roi, 8-channel group), 256 threads.
// LDS holds the ROI region channel-PAIR-interleaved: float2{ch2p, ch2p+1} at
// index (row*33+col)*5 + p. One phase-2 thread = 1 pixel x 2 channels: each
// bilinear corner is a single ds_read_b64 and weights/addresses amortize 2x.
__global__ __launch_bounds__(256, 4) void roi_align_kernel(
    const float* __restrict__ feat,
    const float* __restrict__ rois,
    float* __restrict__ out,
    int C, int H, int W)
{
    const int n    = blockIdx.x;
    const int cblk = blockIdx.y;
    const int t    = threadIdx.x;

    __shared__ float2 s_feat2[S2LEN];
    __shared__ int4   s_ypack[28];   // {(lo-y0)*165, (hi-y0)*165, bits(wy0), bits(wy1)}
    __shared__ int4   s_xpack[28];   // {(xlo-x0a)*5, (xhi-x0a)*5, bits(wx0), bits(wx1)}

    const float* roi = rois + (size_t)n * 5;
    const int   b  = (int)roi[0];
    const float x1 = roi[1], y1 = roi[2], x2 = roi[3], y2 = roi[4];
    const float roi_w = fmaxf(x2 - x1, 1.0f);
    const float roi_h = fmaxf(y2 - y1, 1.0f);
    const float bin_h = roi_h / 7.0f;
    const float bin_w = roi_w / 7.0f;
    int gh = (int)ceilf(roi_h / 7.0f); gh = min(max(gh, 1), MAXG);
    int gw = (int)ceilf(roi_w / 7.0f); gw = min(max(gw, 1), MAXG);
    const float inv_count = 1.0f / (float)(gh * gw);

    auto lo_of = [](float pos, int size) {
        float p = fmaxf(pos, 0.0f);
        return min((int)floorf(p), size - 1);
    };
    const int y0 = lo_of(y1 + 0.5f * bin_h / (float)gh, H);
    const int yE = min(lo_of(y1 + 6.0f * bin_h + ((float)(gh - 1) + 0.5f) * bin_h / (float)gh, H) + 1, H - 1);
    const int x0 = lo_of(x1 + 0.5f * bin_w / (float)gw, W);
    const int xE = min(lo_of(x1 + 6.0f * bin_w + ((float)(gw - 1) + 0.5f) * bin_w / (float)gw, W) + 1, W - 1);
    const int rh    = min(yE - y0 + 1, 30);
    const int x0a   = x0 & ~3;                   // 16B-align region start
    const int spanA = min(xE - x0a + 1, 33);     // cols needed from x0a (<=33)
    const int CM    = W - 4 - x0a;               // max in-row aligned quad start

    // --- geometry tables (premultiplied into float2-index units)
    if (t < 28) {
        const int py = t >> 2, g = t & 3;
        float pos  = y1 + (float)py * bin_h + ((float)g + 0.5f) * bin_h / (float)gh;
        bool valid = (pos >= -1.0f) && (pos <= (float)H);
        float p = fmaxf(pos, 0.0f);
        int lo  = min((int)floorf(p), H - 1);
        int hi  = min(lo + 1, H - 1);
        if (lo >= H - 1) p = (float)(H - 1);
        float frac = p - (float)lo;
        float m = valid ? 1.0f : 0.0f;
        s_ypack[t] = make_int4((lo - y0) * YMUL, (hi - y0) * YMUL,
                               __float_as_int((1.0f - frac) * m),
                               __float_as_int(frac * m));
    } else if (t < 56) {
        const int u = t - 28;
        const int px = u >> 2, g = u & 3;
        float pos  = x1 + (float)px * bin_w + ((float)g + 0.5f) * bin_w / (float)gw;
        bool valid = (pos >= -1.0f) && (pos <= (float)W);
        float p = fmaxf(pos, 0.0f);
        int lo  = min((int)floorf(p), W - 1);
        int hi  = min(lo + 1, W - 1);
        if (lo >= W - 1) p = (float)(W - 1);
        float frac = p - (float)lo;
        float m = valid ? 1.0f : 0.0f;
        s_xpack[u] = make_int4((lo - x0a) * PSTRIDE, (hi - x0a) * PSTRIDE,
                               __float_as_int((1.0f - frac) * m),
                               __float_as_int(frac * m));
    }

    // --- staging: transpose [ch][row][col] -> pair-interleaved LDS
    // slot: pair p = t&3, quad q = (t>>2)&7, row base r0 = t>>5 (stride 8)
    {
        const int  p    = t & 3;
        const int  q    = (t >> 2) & 7;
        const int  r0   = t >> 5;
        const int  q4   = q << 2;
        const bool qon  = (q4 < spanA);
        const int  colA = min(q4, CM);           // in-row aligned; dup writes benign
        const bool tail = (q == 7) && (spanA == 33);

        const size_t HW = (size_t)H * W;
        const int c0 = cblk * CPB;
        const float* fbase = feat + ((size_t)b * C + c0) * HW + (size_t)y0 * W + x0a;
        const float* ga = fbase + (size_t)(2 * p) * HW;
        float2* sb = s_feat2 + p;

        #pragma unroll
        for (int k = 0; k < 4; ++k) {
            const int r = r0 + (k << 3);
            if (r < rh) {
                const float* gp = ga + (size_t)r * W;
                if (qon) {
                    const float4 va = *(const float4*)(gp + colA);
                    const float4 vb = *(const float4*)(gp + HW + colA);
                    float2* sp = sb + (r * UCOLS + colA) * PSTRIDE;
                    sp[0]           = make_float2(va.x, vb.x);
                    sp[PSTRIDE]     = make_float2(va.y, vb.y);
                    sp[2 * PSTRIDE] = make_float2(va.z, vb.z);
                    sp[3 * PSTRIDE] = make_float2(va.w, vb.w);
                }
                if (tail) {                      // col 32 (x0a+32 <= W-1 here)
                    sb[(r * UCOLS + 32) * PSTRIDE] = make_float2(gp[32], gp[HW + 32]);
                }
            }
        }
    }
    __syncthreads();

    // --- compute: thread = (pixel t>>2, channel-pair t&3); taps are b64 reads
    if (t < 196) {
        const int p   = t & 3;
        const int pix = t >> 2;
        const int py  = pix / 7;
        const int px  = pix - py * 7;
        const float2* sp = s_feat2 + p;

        int4 xp[4];
        #pragma unroll
        for (int g = 0; g < 4; ++g) xp[g] = s_xpack[(px << 2) + g];

        float ax = 0.0f, ay = 0.0f;
        #pragma unroll
        for (int gy = 0; gy < MAXG; ++gy) {
            if (gy < gh) {
                const int4 yp = s_ypack[(py << 2) + gy];
                const float wy0 = __int_as_float(yp.z);
                const float wy1 = __int_as_float(yp.w);
                #pragma unroll
                for (int gx = 0; gx < MAXG; ++gx) {
                    if (gx < gw) {
                        const float wx0 = __int_as_float(xp[gx].z);
                        const float wx1 = __int_as_float(xp[gx].w);
                        const float2 v00 = sp[yp.x + xp[gx].x];
                        const float2 v01 = sp[yp.x + xp[gx].y];
                        const float2 v10 = sp[yp.y + xp[gx].x];
                        const float2 v11 = sp[yp.y + xp[gx].y];
                        ax += wy0 * (wx0 * v00.x + wx1 * v01.x)
                            + wy1 * (wx0 * v10.x + wx1 * v11.x);
                        ay += wy0 * (wx0 * v00.y + wx1 * v01.y)
                            + wy1 * (wx0 * v10.y + wx1 * v11.y);
                    }
                }
            }
        }
        const size_t ob = ((size_t)n * C + cblk * CPB + 2 * p) * 49 + pix;
        out[ob]      = ax * inv_count;   // channel 2p
        out[ob + 49] = ay * inv_count;   // channel 2p+1
    }
}

extern "C" void kernel_launch(void* const* d_in, const int* in_sizes, int n_in,
                              void* d_out, int out_size, void* d_ws, size_t ws_size,
                              hipStream_t stream) {
    const float* feat = (const float*)d_in[0];
    const float* rois = (const float*)d_in[1];
    float* out = (float*)d_out;

    const int C = 256, H = 200, W = 272;
    const int N = in_sizes[1] / 5;   // 512

    dim3 grid(N, C / CPB);           // 512 x 32
    roi_align_kernel<<<grid, 256, 0, stream>>>(feat, rois, out, C, H, W);
}